// Round 5
// baseline (619.406 us; speedup 1.0000x reference)
//
#include <hip/hip_runtime.h>
#include <cmath>

// ---------------------------------------------------------------------------
// MLLA block, B=8 L=2048 C=512 H=8 HD=64 MLP_H=2048, fp32 I/O, bf16 MFMA GEMMs
// R5: attn rewritten on MFMA: kvmat stored transposed+bf16, q@kvmatT and
//     z=q.k_mean both via mfma_16x16x32; serial 16-token loop removed.
// ---------------------------------------------------------------------------

typedef __bf16 bf16;
typedef __bf16 bf16x8 __attribute__((ext_vector_type(8)));
typedef __bf16 bf16x4 __attribute__((ext_vector_type(4)));
typedef float  f32x4  __attribute__((ext_vector_type(4)));

#define B_  8
#define L_  2048
#define C_  512
#define M_  (B_ * L_)          // 16384 tokens

__device__ __forceinline__ float siluf(float x) { return x / (1.f + __expf(-x)); }
__device__ __forceinline__ float elu1f(float x) { return x > 0.f ? x + 1.f : __expf(x); }
__device__ __forceinline__ float geluf(float x) { return 0.5f * x * (1.f + erff(x * 0.70710678118654752f)); }

// global -> LDS direct DMA, 16B per lane. lds dest must be wave-uniform base;
// HW deposits lane i at base + i*16B.
__device__ __forceinline__ void load_lds16(const bf16* g, bf16* l)
{
    __builtin_amdgcn_global_load_lds(
        (const __attribute__((address_space(1))) void*)g,
        (__attribute__((address_space(3))) void*)l, 16, 0, 0);
}

// ---------------------------------------------------------------------------
__global__ __launch_bounds__(256) void zero_k(float* __restrict__ p, int n)
{
    int i = blockIdx.x * 256 + threadIdx.x;
    if (i < n) p[i] = 0.f;
}

__global__ __launch_bounds__(64) void ws_diag_k(float* __restrict__ out, float v)
{
    if (threadIdx.x == 0 && blockIdx.x == 0) out[0] = v;
}

// ---------------------------------------------------------------------------
// fp32 -> bf16 elementwise (vectorized x4)
// ---------------------------------------------------------------------------
__global__ __launch_bounds__(256) void f32_to_bf16_k(
    const float* __restrict__ in, bf16* __restrict__ out, int n4)
{
    int i = blockIdx.x * 256 + threadIdx.x;
    if (i >= n4) return;
    float4 v = ((const float4*)in)[i];
    bf16x4 o = { (bf16)v.x, (bf16)v.y, (bf16)v.z, (bf16)v.w };
    ((bf16x4*)out)[i] = o;
}

// ---------------------------------------------------------------------------
// fp32 (K x N) -> bf16 transposed (N x K), 32x32 LDS tile
// ---------------------------------------------------------------------------
__global__ __launch_bounds__(256) void transpose_bf16_k(
    const float* __restrict__ W, bf16* __restrict__ Wt, int K, int N)
{
    __shared__ float tile[32][33];
    const int n0 = blockIdx.x * 32, k0 = blockIdx.y * 32;
    const int tx = threadIdx.x & 31, ty = threadIdx.x >> 5;   // 32 x 8
#pragma unroll
    for (int i = 0; i < 32; i += 8)
        tile[ty + i][tx] = W[(size_t)(k0 + ty + i) * N + n0 + tx];
    __syncthreads();
#pragma unroll
    for (int i = 0; i < 32; i += 8)
        Wt[(size_t)(n0 + ty + i) * K + k0 + tx] = (bf16)tile[tx][ty + i];
}

// ---------------------------------------------------------------------------
// depthwise conv (k=3, zero pad) along L + residual + LayerNorm.
// ---------------------------------------------------------------------------
__global__ __launch_bounds__(256) void cpe_ln_k(
    const float* __restrict__ xin, const float* __restrict__ cw,
    const float* __restrict__ cb, const float* __restrict__ g,
    const float* __restrict__ bb, float* __restrict__ xres,
    bf16* __restrict__ xln)
{
    const int token = blockIdx.x;
    const int l = token & (L_ - 1);
    const int tid = threadIdx.x;
    const float* row = xin + (size_t)token * C_;
    float v[2]; float s = 0.f, s2 = 0.f;
#pragma unroll
    for (int i = 0; i < 2; ++i) {
        const int c = tid + i * 256;
        float x0 = row[c];
        float xm = (l > 0)      ? row[c - C_] : 0.f;
        float xp = (l < L_ - 1) ? row[c + C_] : 0.f;
        float t = x0 + xm * cw[3*c] + x0 * cw[3*c+1] + xp * cw[3*c+2] + cb[c];
        v[i] = t; s += t; s2 += t * t;
    }
#pragma unroll
    for (int off = 32; off; off >>= 1) { s += __shfl_down(s, off); s2 += __shfl_down(s2, off); }
    __shared__ float rs[4], rs2[4];
    if ((tid & 63) == 0) { rs[tid >> 6] = s; rs2[tid >> 6] = s2; }
    __syncthreads();
    s  = rs[0] + rs[1] + rs[2] + rs[3];
    s2 = rs2[0] + rs2[1] + rs2[2] + rs2[3];
    const float mu = s * (1.f / C_);
    const float rstd = rsqrtf(s2 * (1.f / C_) - mu * mu + 1e-5f);
    float* orow = xres + (size_t)token * C_;
    bf16*  lrow = xln  + (size_t)token * C_;
#pragma unroll
    for (int i = 0; i < 2; ++i) {
        const int c = tid + i * 256;
        orow[c] = v[i];
        lrow[c] = (bf16)((v[i] - mu) * rstd * g[c] + bb[c]);
    }
}

// ---------------------------------------------------------------------------
// dwc conv over the (b,c,l)-reinterpreted flat buffer + SiLU.
// ---------------------------------------------------------------------------
__global__ __launch_bounds__(256) void dwc_silu_k(
    const bf16* __restrict__ Y, const float* __restrict__ w,
    const float* __restrict__ b, bf16* __restrict__ xp)
{
    const size_t idx = (size_t)blockIdx.x * 256 + threadIdx.x;   // over B_*L_*C_
    const int m = (int)(idx & (size_t)(L_ * C_ - 1));
    const int ch = m >> 11;          // m / 2048
    const int pos = m & (L_ - 1);
    float x0 = (float)Y[idx];
    float xm = (pos > 0)      ? (float)Y[idx - 1] : 0.f;
    float xq = (pos < L_ - 1) ? (float)Y[idx + 1] : 0.f;
    float t = xm * w[3*ch] + x0 * w[3*ch+1] + xq * w[3*ch+2] + b[ch];
    xp[idx] = (bf16)siluf(t);
}

// ---------------------------------------------------------------------------
// ksum[b, c] = sum_n k[b,n,c] from kvbT rows (c-major): contiguous reduction.
// ---------------------------------------------------------------------------
__global__ __launch_bounds__(256) void ksum_k(
    const bf16* __restrict__ kvbT, float* __restrict__ ksum)
{
    const int c = blockIdx.x;
    const int wave = threadIdx.x >> 6, lane = threadIdx.x & 63;
#pragma unroll
    for (int i = 0; i < 2; ++i) {
        const int b = wave + i * 4;
        const bf16* src = kvbT + (size_t)c * M_ + b * L_ + lane * 32;
        float s = 0.f;
#pragma unroll
        for (int u = 0; u < 4; ++u) {
            bf16x8 v = *(const bf16x8*)(src + u * 8);
#pragma unroll
            for (int j = 0; j < 8; ++j) s += (float)v[j];
        }
#pragma unroll
        for (int o = 32; o; o >>= 1) s += __shfl_down(s, o);
        if (lane == 0) ksum[b * C_ + c] = s;
    }
}

// ---------------------------------------------------------------------------
// kvmatT[b,h,e,d] = (1/L) * sum_n v[b,n,h,e] * k[b,n,h,d]   (TRANSPOSED)
// via MFMA: A = v rows, B = k rows of kvbT. f32 atomic accumulate.
// ---------------------------------------------------------------------------
__global__ __launch_bounds__(256) void kvmat_mfma_k(
    const bf16* __restrict__ kvbT, float* __restrict__ kvmatT)
{
    const int bh = blockIdx.x, b = bh >> 3, h = bh & 7;
    const int tid = threadIdx.x;
    const int wave = tid >> 6, lane = tid & 63;
    const int l16 = lane & 15, quad = lane >> 4;
    __shared__ bf16 As[64 * 72];   // vT chunk: [e][n]
    __shared__ bf16 Bs[64 * 72];   // kT chunk: [d][n]
    const int r = tid >> 2;              // 0..63: LDS row
    const int cseg = (tid & 3) * 16;     // 16 bf16 per thread
    const size_t kRow = (size_t)(h * 64 + r) * M_;
    const size_t vRow = (size_t)(512 + h * 64 + r) * M_;

    f32x4 acc[4];
    const f32x4 z4 = { 0.f, 0.f, 0.f, 0.f };
#pragma unroll
    for (int ni = 0; ni < 4; ++ni) acc[ni] = z4;

    for (int it = 0; it < 8; ++it) {
        const size_t colBase = (size_t)b * L_ + blockIdx.y * 512 + it * 64;
        {
            const bf16* ga = kvbT + vRow + colBase + cseg;   // A = v
            const bf16* gb = kvbT + kRow + colBase + cseg;   // B = k
            *(uint4*)&As[r * 72 + cseg]     = *(const uint4*)ga;
            *(uint4*)&As[r * 72 + cseg + 8] = *(const uint4*)(ga + 8);
            *(uint4*)&Bs[r * 72 + cseg]     = *(const uint4*)gb;
            *(uint4*)&Bs[r * 72 + cseg + 8] = *(const uint4*)(gb + 8);
        }
        __syncthreads();
#pragma unroll
        for (int kk = 0; kk < 64; kk += 32) {
            bf16x8 af = *(const bf16x8*)(&As[(wave * 16 + l16) * 72 + kk + quad * 8]);
#pragma unroll
            for (int ni = 0; ni < 4; ++ni) {
                bf16x8 bfr = *(const bf16x8*)(&Bs[(ni * 16 + l16) * 72 + kk + quad * 8]);
                acc[ni] = __builtin_amdgcn_mfma_f32_16x16x32_bf16(af, bfr, acc[ni], 0, 0, 0);
            }
        }
        __syncthreads();
    }
    const float sc = 1.f / (float)L_;
    float* dst = kvmatT + (size_t)bh * 4096;    // [e][d]
#pragma unroll
    for (int ni = 0; ni < 4; ++ni)
#pragma unroll
        for (int rr = 0; rr < 4; ++rr)
            atomicAdd(&dst[(wave * 16 + quad * 4 + rr) * 64 + ni * 16 + l16],
                      acc[ni][rr] * sc);
}

// f32 kvmatT -> bf16 (262144 elems)
__global__ __launch_bounds__(256) void kvconv_k(
    const float* __restrict__ in, bf16* __restrict__ out)
{
    int i = blockIdx.x * 256 + threadIdx.x;
    out[i] = (bf16)in[i];
}

// ---------------------------------------------------------------------------
// MFMA attention: per block (bh, 64-token tile); per wave 16 tokens.
// out[n][e] = (q @ kvmatT^T)*z + lepe(v);  xamul = out * act_res.
// z = 1/(q.k_mean+1e-6) via MFMA with B-tile whose col0 = k_mean.
// ---------------------------------------------------------------------------
__global__ __launch_bounds__(256) void attn_mfma_k(
    const bf16* __restrict__ q, const bf16* __restrict__ kvbT,
    const bf16* __restrict__ kvmatT, const float* __restrict__ ksum,
    const float* __restrict__ lw, const float* __restrict__ lb,
    const bf16* __restrict__ act_res, bf16* __restrict__ xa_mul)
{
    const int bh = blockIdx.x, b = bh >> 3, h = bh & 7;
    const int n0 = blockIdx.y * 64;
    const int tid = threadIdx.x;
    const int wave = tid >> 6, lane = tid & 63;
    const int l16 = lane & 15, quad = lane >> 4;

    __shared__ bf16 kvT[64 * 72];   // [e][d], stride 72 kills conflicts
    __shared__ bf16 kmS[64];

#pragma unroll
    for (int i = 0; i < 2; ++i) {
        const int idx = i * 256 + tid;               // 512 chunks of 8
        const int row = idx >> 3, col = (idx & 7) * 8;
        *(bf16x8*)&kvT[row * 72 + col] =
            *(const bf16x8*)&kvmatT[(size_t)bh * 4096 + idx * 8];
    }
    if (tid < 64) kmS[tid] = (bf16)(ksum[b * C_ + h * 64 + tid] * (1.f / (float)L_));
    __syncthreads();

    // A-frags: 16 q-rows direct from global. token m = l16, k = ks*32+quad*8+j
    const int tok = n0 + wave * 16;
    const bf16* qbase = q + ((size_t)b * L_ + tok) * C_ + h * 64;
    const bf16x8 af0 = *(const bf16x8*)(qbase + (size_t)l16 * C_ + quad * 8);
    const bf16x8 af1 = *(const bf16x8*)(qbase + (size_t)l16 * C_ + 32 + quad * 8);

    // z-dot: B2 col0 = km
    const bf16x8 z8 = { bf16(0.f), bf16(0.f), bf16(0.f), bf16(0.f),
                        bf16(0.f), bf16(0.f), bf16(0.f), bf16(0.f) };
    const bf16x8 km0 = *(const bf16x8*)&kmS[quad * 8];
    const bf16x8 km1 = *(const bf16x8*)&kmS[32 + quad * 8];
    const bf16x8 b20 = (l16 == 0) ? km0 : z8;
    const bf16x8 b21 = (l16 == 0) ? km1 : z8;
    f32x4 zd = { 0.f, 0.f, 0.f, 0.f };
    zd = __builtin_amdgcn_mfma_f32_16x16x32_bf16(af0, b20, zd, 0, 0, 0);
    zd = __builtin_amdgcn_mfma_f32_16x16x32_bf16(af1, b21, zd, 0, 0, 0);
    // z for token row quad*4+r lives in lane quad*16, reg r -> broadcast
    float zr[4];
#pragma unroll
    for (int r = 0; r < 4; ++r)
        zr[r] = 1.f / (__shfl(zd[r], (lane & 48)) + 1e-6f);

    // q @ kvmatT^T
    f32x4 acc[4];
    const f32x4 zf4 = { 0.f, 0.f, 0.f, 0.f };
#pragma unroll
    for (int ni = 0; ni < 4; ++ni) acc[ni] = zf4;
#pragma unroll
    for (int ni = 0; ni < 4; ++ni) {
        const bf16x8 b0 = *(const bf16x8*)&kvT[(ni * 16 + l16) * 72 + quad * 8];
        const bf16x8 b1 = *(const bf16x8*)&kvT[(ni * 16 + l16) * 72 + 32 + quad * 8];
        acc[ni] = __builtin_amdgcn_mfma_f32_16x16x32_bf16(af0, b0, acc[ni], 0, 0, 0);
        acc[ni] = __builtin_amdgcn_mfma_f32_16x16x32_bf16(af1, b1, acc[ni], 0, 0, 0);
    }

    // epilogue: lane holds (token = tok+quad*4+r, e = ni*16+l16)
#pragma unroll
    for (int ni = 0; ni < 4; ++ni) {
        const int e = ni * 16 + l16;
        const int c = h * 64 + e;
        const float w0 = lw[3*c], w1 = lw[3*c+1], w2 = lw[3*c+2], lbc = lb[c];
        const bf16* vrow = kvbT + (size_t)(512 + c) * M_ + b * L_;
#pragma unroll
        for (int r = 0; r < 4; ++r) {
            const int n = tok + quad * 4 + r;
            const float v0 = (float)vrow[n];
            const float vm = (n > 0)      ? (float)vrow[n - 1] : 0.f;
            const float vp = (n < L_ - 1) ? (float)vrow[n + 1] : 0.f;
            const float lepe = vm * w0 + v0 * w1 + vp * w2 + lbc;
            const float xa = acc[ni][r] * zr[r] + lepe;
            const size_t off = ((size_t)b * L_ + n) * C_ + c;
            xa_mul[off] = (bf16)(xa * (float)act_res[off]);
        }
    }
}

// ---------------------------------------------------------------------------
// bf16 MFMA GEMM, m97 structure: global_load_lds width=16 staging, unpadded
// 128x64 LDS tiles, BM=BN=128 BK=64, 4 waves each 64x64.
// EPI: 2 elu+1->bf16, 4 gelu->bf16, 5 +res->f32, 7 kvT (row<512 elu)->bf16,
//      8 fused act/in: col<512 silu->outp, else plain->outp2 (res = 2nd bias)
// ---------------------------------------------------------------------------
template <int EPI>
__global__ __launch_bounds__(256) void gemm_bt(
    const bf16* __restrict__ A, const bf16* __restrict__ Bt,
    const float* __restrict__ bias, const float* __restrict__ res,
    void* __restrict__ outp, void* __restrict__ outp2, int K, int N)
{
    __shared__ bf16 As[128 * 64];
    __shared__ bf16 Bs[128 * 64];
    const int tid = threadIdx.x;
    const int wave = tid >> 6, lane = tid & 63;
    const int wm = (wave & 1) * 64, wn = (wave >> 1) * 64;
    const int l16 = lane & 15, quad = lane >> 4;
    const size_t tileM = (size_t)blockIdx.x * 128;
    const size_t tileN = (size_t)blockIdx.y * 128;

    const int lrow = lane >> 3;
    const int lcol = (lane & 7) * 8;

    const f32x4 z4 = { 0.f, 0.f, 0.f, 0.f };
    f32x4 acc[4][4];
#pragma unroll
    for (int mi = 0; mi < 4; ++mi)
#pragma unroll
        for (int ni = 0; ni < 4; ++ni) acc[mi][ni] = z4;

    for (int k0 = 0; k0 < K; k0 += 64) {
#pragma unroll
        for (int it = 0; it < 4; ++it) {
            const int rg = it * 32 + wave * 8;           // wave-uniform
            load_lds16(A  + (tileM + rg + lrow) * (size_t)K + k0 + lcol, As + rg * 64);
            load_lds16(Bt + (tileN + rg + lrow) * (size_t)K + k0 + lcol, Bs + rg * 64);
        }
        __syncthreads();
#pragma unroll
        for (int kk = 0; kk < 64; kk += 32) {
            bf16x8 af[4], bfr[4];
#pragma unroll
            for (int mi = 0; mi < 4; ++mi)
                af[mi] = *(const bf16x8*)(&As[(wm + mi * 16 + l16) * 64 + kk + quad * 8]);
#pragma unroll
            for (int ni = 0; ni < 4; ++ni)
                bfr[ni] = *(const bf16x8*)(&Bs[(wn + ni * 16 + l16) * 64 + kk + quad * 8]);
#pragma unroll
            for (int mi = 0; mi < 4; ++mi)
#pragma unroll
                for (int ni = 0; ni < 4; ++ni)
                    acc[mi][ni] = __builtin_amdgcn_mfma_f32_16x16x32_bf16(
                        af[mi], bfr[ni], acc[mi][ni], 0, 0, 0);
        }
        __syncthreads();
    }

#pragma unroll
    for (int mi = 0; mi < 4; ++mi) {
#pragma unroll
        for (int ni = 0; ni < 4; ++ni) {
#pragma unroll
            for (int r = 0; r < 4; ++r) {
                const size_t row = tileM + wm + mi * 16 + quad * 4 + r;
                const int   col = (int)tileN + wn + ni * 16 + l16;
                float v = acc[mi][ni][r];
                const size_t oidx = row * (size_t)N + col;
                if (EPI == 2)      ((bf16*)outp)[oidx] = (bf16)elu1f(v + bias[col]);
                else if (EPI == 4) ((bf16*)outp)[oidx] = (bf16)geluf(v + bias[col]);
                else if (EPI == 5) ((float*)outp)[oidx] = v + bias[col] + res[oidx];
                else if (EPI == 7) {
                    v += bias[(int)row];
                    ((bf16*)outp)[oidx] = (bf16)((row < 512) ? elu1f(v) : v);
                } else if (EPI == 8) {
                    const size_t orow = row * (size_t)512;
                    if (col < 512) ((bf16*)outp )[orow + col]       = (bf16)siluf(v + bias[col]);
                    else           ((bf16*)outp2)[orow + col - 512] = (bf16)(v + res[col - 512]);
                }
            }
        }
    }
}

// ---------------------------------------------------------------------------
// workspace layout (bytes) — total 125,845,504 (~120 MiB)
// ---------------------------------------------------------------------------
#define OFF_WT_ACTIN ((size_t)0)         // bf16 [1024][512] 1MB
#define OFF_WT_Q    ((size_t)1048576)
#define OFF_WT_KV   ((size_t)1572864)
#define OFF_WT_OUT  ((size_t)2621440)
#define OFF_WT_FC1  ((size_t)3145728)
#define OFF_WT_FC2  ((size_t)5242880)
#define OFF_XLN     ((size_t)7340032)    // bf16 16MB (xqb, kvbf, hln alias)
#define OFF_ACTRES  ((size_t)24117248)   // bf16 16MB (x3 aliases from here)
#define OFF_Y       ((size_t)40894464)   // bf16 16MB (qb aliases)
#define OFF_XP      ((size_t)57671680)   // bf16 16MB (h1 aliases from here)
#define OFF_KV      ((size_t)74448896)   // bf16 32MB  kvbT [1024][16384]
#define OFF_KSUM    ((size_t)108003328)  // f32 16KB
#define OFF_KVMAT   ((size_t)108019712)  // f32 1MB
#define OFF_XAMUL   ((size_t)109068288)  // bf16 16MB  -> end 125845504
#define OFF_X3      ((size_t)24117248)   // f32 32MB over actres+Y (dead)
#define OFF_H1      ((size_t)57671680)   // bf16 64MB over xp+kv+kvmat+xamul (dead)
#define WS_REQUIRED ((size_t)125845504)

extern "C" void kernel_launch(void* const* d_in, const int* in_sizes, int n_in,
                              void* d_out, int out_size, void* d_ws, size_t ws_size,
                              hipStream_t stream)
{
    const float* x_q    = (const float*)d_in[0];
    const float* x_kv   = (const float*)d_in[1];
    const float* cpe1_w = (const float*)d_in[2];
    const float* cpe1_b = (const float*)d_in[3];
    const float* n1_g   = (const float*)d_in[4];
    const float* n1_b   = (const float*)d_in[5];
    const float* in_w   = (const float*)d_in[6];
    const float* in_b   = (const float*)d_in[7];
    const float* act_w  = (const float*)d_in[8];
    const float* act_b  = (const float*)d_in[9];
    const float* dwc_w  = (const float*)d_in[10];
    const float* dwc_b  = (const float*)d_in[11];
    const float* q_w    = (const float*)d_in[12];
    const float* q_b    = (const float*)d_in[13];
    const float* kv_w   = (const float*)d_in[14];
    const float* kv_b   = (const float*)d_in[15];
    const float* lepe_w = (const float*)d_in[16];
    const float* lepe_b = (const float*)d_in[17];
    const float* out_w  = (const float*)d_in[18];
    const float* out_b  = (const float*)d_in[19];
    const float* cpe2_w = (const float*)d_in[20];
    const float* cpe2_b = (const float*)d_in[21];
    const float* n2_g   = (const float*)d_in[22];
    const float* n2_b   = (const float*)d_in[23];
    const float* fc1_w  = (const float*)d_in[24];
    const float* fc1_b  = (const float*)d_in[25];
    const float* fc2_w  = (const float*)d_in[26];
    const float* fc2_b  = (const float*)d_in[27];

    float* outf = (float*)d_out;

    if (ws_size < WS_REQUIRED) {
        zero_k<<<(out_size + 255) / 256, 256, 0, stream>>>(outf, out_size);
        ws_diag_k<<<1, 64, 0, stream>>>(outf, (float)ws_size);
        return;
    }

    char* ws = (char*)d_ws;
    bf16*  wt_actin = (bf16*)(ws + OFF_WT_ACTIN);
    bf16*  wt_q   = (bf16*)(ws + OFF_WT_Q);
    bf16*  wt_kv  = (bf16*)(ws + OFF_WT_KV);
    bf16*  wt_out = (bf16*)(ws + OFF_WT_OUT);
    bf16*  wt_fc1 = (bf16*)(ws + OFF_WT_FC1);
    bf16*  wt_fc2 = (bf16*)(ws + OFF_WT_FC2);
    bf16*  xln    = (bf16*)(ws + OFF_XLN);
    bf16*  xqb    = (bf16*)(ws + OFF_XLN);      // alias: xln dead after act/in
    bf16*  kvbf   = (bf16*)(ws + OFF_XLN);      // alias: xqb dead after q-gemm
    bf16*  hln    = (bf16*)(ws + OFF_XLN);      // alias: kvbf dead after attn
    bf16*  actres = (bf16*)(ws + OFF_ACTRES);
    bf16*  Y      = (bf16*)(ws + OFF_Y);
    bf16*  qb     = (bf16*)(ws + OFF_Y);        // alias: Y dead after dwc
    bf16*  xp     = (bf16*)(ws + OFF_XP);
    bf16*  kvbT   = (bf16*)(ws + OFF_KV);       // [1024][16384]
    float* ksum   = (float*)(ws + OFF_KSUM);
    float* kvmatT = (float*)(ws + OFF_KVMAT);
    bf16*  xamul  = (bf16*)(ws + OFF_XAMUL);
    float* x3     = (float*)(ws + OFF_X3);      // alias
    bf16*  h1     = (bf16*)(ws + OFF_H1);       // alias

    // zero kvmatT atomic accumulator (f32, 64*4096 elems)
    zero_k<<<1024, 256, 0, stream>>>(kvmatT, 262144);

    // weight convert + transpose (W KxN -> Wt NxK bf16)
    transpose_bf16_k<<<dim3(16, 16), 256, 0, stream>>>(act_w, wt_actin, 512, 512);
    transpose_bf16_k<<<dim3(16, 16), 256, 0, stream>>>(in_w,  wt_actin + 512 * 512, 512, 512);
    transpose_bf16_k<<<dim3(16, 16), 256, 0, stream>>>(q_w,   wt_q,   512, 512);
    transpose_bf16_k<<<dim3(32, 16), 256, 0, stream>>>(kv_w,  wt_kv,  512, 1024);
    transpose_bf16_k<<<dim3(16, 16), 256, 0, stream>>>(out_w, wt_out, 512, 512);
    transpose_bf16_k<<<dim3(64, 16), 256, 0, stream>>>(fc1_w, wt_fc1, 512, 2048);
    transpose_bf16_k<<<dim3(16, 64), 256, 0, stream>>>(fc2_w, wt_fc2, 2048, 512);

    // cpe1 + LN1: shortcut (fp32) lives in d_out
    cpe_ln_k<<<M_, 256, 0, stream>>>(x_kv, cpe1_w, cpe1_b, n1_g, n1_b, outf, xln);

    // fused act gate + in-proj (one pass over xln), N=1024
    gemm_bt<8><<<dim3(128, 8), 256, 0, stream>>>(xln, wt_actin, act_b, in_b, actres, Y, 512, 1024);

    // flat-reshape dwconv + silu -> xp (frees Y)
    dwc_silu_k<<<32768, 256, 0, stream>>>(Y, dwc_w, dwc_b, xp);

    // x_q -> bf16 (into dead xln region), then q = elu+1(xqb @ q_w) -> qb (@Y)
    f32_to_bf16_k<<<8192, 256, 0, stream>>>(x_q, xqb, M_ * C_ / 4);
    gemm_bt<2><<<dim3(128, 4), 256, 0, stream>>>(xqb, wt_q, q_b, nullptr, qb, nullptr, 512, 512);

    // kvbT[c][token] = (xp @ kv_w)^T : roles swapped (A=wt_kv, Bt=xp)
    gemm_bt<7><<<dim3(8, 128), 256, 0, stream>>>(wt_kv, xp, kv_b, nullptr, kvbT, nullptr, 512, M_);

    // k_mean, kvmatT (MFMA, transposed), bf16 convert (into dead xqb region)
    ksum_k<<<C_, 256, 0, stream>>>(kvbT, ksum);
    kvmat_mfma_k<<<dim3(64, 4), 256, 0, stream>>>(kvbT, kvmatT);
    kvconv_k<<<1024, 256, 0, stream>>>(kvmatT, kvbf);

    // MFMA attention + lepe + gate multiply
    attn_mfma_k<<<dim3(64, 32), 256, 0, stream>>>(qb, kvbT, kvbf, ksum,
                                                  lepe_w, lepe_b, actres, xamul);

    // out-proj + shortcut residual, in-place on d_out
    gemm_bt<5><<<dim3(128, 4), 256, 0, stream>>>(xamul, wt_out, out_b, outf, outf, nullptr, 512, 512);

    // cpe2 + LN2: x2 (=d_out) -> x3 (fp32 ws) + hln (bf16)
    cpe_ln_k<<<M_, 256, 0, stream>>>(outf, cpe2_w, cpe2_b, n2_g, n2_b, x3, hln);

    // MLP: fc1 (exact gelu) -> fc2 (+x3) -> d_out
    gemm_bt<4><<<dim3(128, 16), 256, 0, stream>>>(hln, wt_fc1, fc1_b, nullptr, h1, nullptr, 512, 2048);
    gemm_bt<5><<<dim3(128, 4),  256, 0, stream>>>(h1,  wt_fc2, fc2_b, x3, outf, nullptr, 2048, 512);

    (void)in_sizes; (void)n_in; (void)out_size; (void)ws_size;
}

// Round 6
// 548.999 us; speedup vs baseline: 1.1282x; 1.1282x over previous
//
#include <hip/hip_runtime.h>
#include <cmath>

// ---------------------------------------------------------------------------
// MLLA block, B=8 L=2048 C=512 H=8 HD=64 MLP_H=2048, fp32 I/O, bf16 MFMA GEMMs
// R6: erff -> A&S 7.1.26 rational erf (epilogue was VALU-bound: 33.5M erff
//     calls dominated fc1); kvmat partial-buffer reduction (no atomics/zero).
// ---------------------------------------------------------------------------

typedef __bf16 bf16;
typedef __bf16 bf16x8 __attribute__((ext_vector_type(8)));
typedef __bf16 bf16x4 __attribute__((ext_vector_type(4)));
typedef float  f32x4  __attribute__((ext_vector_type(4)));

#define B_  8
#define L_  2048
#define C_  512
#define M_  (B_ * L_)          // 16384 tokens

__device__ __forceinline__ float siluf(float x) { return x / (1.f + __expf(-x)); }
__device__ __forceinline__ float elu1f(float x) { return x > 0.f ? x + 1.f : __expf(x); }

// exact-GELU via Abramowitz-Stegun 7.1.26 erf (|eps| <= 1.5e-7)
__device__ __forceinline__ float geluf(float x)
{
    const float z = fabsf(x) * 0.70710678118654752f;
    const float t = __frcp_rn(1.f + 0.3275911f * z);
    float poly = 1.061405429f;
    poly = poly * t - 1.453152027f;
    poly = poly * t + 1.421413741f;
    poly = poly * t - 0.284496736f;
    poly = poly * t + 0.254829592f;
    poly = poly * t;
    const float e = poly * __expf(-z * z);        // 1 - erf(z)
    const float erfz = 1.f - e;                   // erf(|x|/sqrt2)
    const float erfs = (x < 0.f) ? -erfz : erfz;
    return 0.5f * x * (1.f + erfs);
}

// global -> LDS direct DMA, 16B per lane. lds dest must be wave-uniform base;
// HW deposits lane i at base + i*16B.
__device__ __forceinline__ void load_lds16(const bf16* g, bf16* l)
{
    __builtin_amdgcn_global_load_lds(
        (const __attribute__((address_space(1))) void*)g,
        (__attribute__((address_space(3))) void*)l, 16, 0, 0);
}

// ---------------------------------------------------------------------------
__global__ __launch_bounds__(256) void zero_k(float* __restrict__ p, int n)
{
    int i = blockIdx.x * 256 + threadIdx.x;
    if (i < n) p[i] = 0.f;
}

__global__ __launch_bounds__(64) void ws_diag_k(float* __restrict__ out, float v)
{
    if (threadIdx.x == 0 && blockIdx.x == 0) out[0] = v;
}

// ---------------------------------------------------------------------------
// fp32 -> bf16 elementwise (vectorized x4)
// ---------------------------------------------------------------------------
__global__ __launch_bounds__(256) void f32_to_bf16_k(
    const float* __restrict__ in, bf16* __restrict__ out, int n4)
{
    int i = blockIdx.x * 256 + threadIdx.x;
    if (i >= n4) return;
    float4 v = ((const float4*)in)[i];
    bf16x4 o = { (bf16)v.x, (bf16)v.y, (bf16)v.z, (bf16)v.w };
    ((bf16x4*)out)[i] = o;
}

// ---------------------------------------------------------------------------
// fp32 (K x N) -> bf16 transposed (N x K), 32x32 LDS tile
// ---------------------------------------------------------------------------
__global__ __launch_bounds__(256) void transpose_bf16_k(
    const float* __restrict__ W, bf16* __restrict__ Wt, int K, int N)
{
    __shared__ float tile[32][33];
    const int n0 = blockIdx.x * 32, k0 = blockIdx.y * 32;
    const int tx = threadIdx.x & 31, ty = threadIdx.x >> 5;   // 32 x 8
#pragma unroll
    for (int i = 0; i < 32; i += 8)
        tile[ty + i][tx] = W[(size_t)(k0 + ty + i) * N + n0 + tx];
    __syncthreads();
#pragma unroll
    for (int i = 0; i < 32; i += 8)
        Wt[(size_t)(n0 + ty + i) * K + k0 + tx] = (bf16)tile[tx][ty + i];
}

// ---------------------------------------------------------------------------
// depthwise conv (k=3, zero pad) along L + residual + LayerNorm.
// ---------------------------------------------------------------------------
__global__ __launch_bounds__(256) void cpe_ln_k(
    const float* __restrict__ xin, const float* __restrict__ cw,
    const float* __restrict__ cb, const float* __restrict__ g,
    const float* __restrict__ bb, float* __restrict__ xres,
    bf16* __restrict__ xln)
{
    const int token = blockIdx.x;
    const int l = token & (L_ - 1);
    const int tid = threadIdx.x;
    const float* row = xin + (size_t)token * C_;
    float v[2]; float s = 0.f, s2 = 0.f;
#pragma unroll
    for (int i = 0; i < 2; ++i) {
        const int c = tid + i * 256;
        float x0 = row[c];
        float xm = (l > 0)      ? row[c - C_] : 0.f;
        float xp = (l < L_ - 1) ? row[c + C_] : 0.f;
        float t = x0 + xm * cw[3*c] + x0 * cw[3*c+1] + xp * cw[3*c+2] + cb[c];
        v[i] = t; s += t; s2 += t * t;
    }
#pragma unroll
    for (int off = 32; off; off >>= 1) { s += __shfl_down(s, off); s2 += __shfl_down(s2, off); }
    __shared__ float rs[4], rs2[4];
    if ((tid & 63) == 0) { rs[tid >> 6] = s; rs2[tid >> 6] = s2; }
    __syncthreads();
    s  = rs[0] + rs[1] + rs[2] + rs[3];
    s2 = rs2[0] + rs2[1] + rs2[2] + rs2[3];
    const float mu = s * (1.f / C_);
    const float rstd = rsqrtf(s2 * (1.f / C_) - mu * mu + 1e-5f);
    float* orow = xres + (size_t)token * C_;
    bf16*  lrow = xln  + (size_t)token * C_;
#pragma unroll
    for (int i = 0; i < 2; ++i) {
        const int c = tid + i * 256;
        orow[c] = v[i];
        lrow[c] = (bf16)((v[i] - mu) * rstd * g[c] + bb[c]);
    }
}

// ---------------------------------------------------------------------------
// dwc conv over the (b,c,l)-reinterpreted flat buffer + SiLU.
// ---------------------------------------------------------------------------
__global__ __launch_bounds__(256) void dwc_silu_k(
    const bf16* __restrict__ Y, const float* __restrict__ w,
    const float* __restrict__ b, bf16* __restrict__ xp)
{
    const size_t idx = (size_t)blockIdx.x * 256 + threadIdx.x;   // over B_*L_*C_
    const int m = (int)(idx & (size_t)(L_ * C_ - 1));
    const int ch = m >> 11;          // m / 2048
    const int pos = m & (L_ - 1);
    float x0 = (float)Y[idx];
    float xm = (pos > 0)      ? (float)Y[idx - 1] : 0.f;
    float xq = (pos < L_ - 1) ? (float)Y[idx + 1] : 0.f;
    float t = xm * w[3*ch] + x0 * w[3*ch+1] + xq * w[3*ch+2] + b[ch];
    xp[idx] = (bf16)siluf(t);
}

// ---------------------------------------------------------------------------
// ksum[b, c] = sum_n k[b,n,c] from kvbT rows (c-major): contiguous reduction.
// ---------------------------------------------------------------------------
__global__ __launch_bounds__(256) void ksum_k(
    const bf16* __restrict__ kvbT, float* __restrict__ ksum)
{
    const int c = blockIdx.x;
    const int wave = threadIdx.x >> 6, lane = threadIdx.x & 63;
#pragma unroll
    for (int i = 0; i < 2; ++i) {
        const int b = wave + i * 4;
        const bf16* src = kvbT + (size_t)c * M_ + b * L_ + lane * 32;
        float s = 0.f;
#pragma unroll
        for (int u = 0; u < 4; ++u) {
            bf16x8 v = *(const bf16x8*)(src + u * 8);
#pragma unroll
            for (int j = 0; j < 8; ++j) s += (float)v[j];
        }
#pragma unroll
        for (int o = 32; o; o >>= 1) s += __shfl_down(s, o);
        if (lane == 0) ksum[b * C_ + c] = s;
    }
}

// ---------------------------------------------------------------------------
// kvpart[split][b,h,e,d] = sum_{n in split} v[b,n,h,e] * k[b,n,h,d]
// via MFMA (transposed layout [e][d]); plain stores, no atomics.
// ---------------------------------------------------------------------------
__global__ __launch_bounds__(256) void kvmat_mfma_k(
    const bf16* __restrict__ kvbT, float* __restrict__ kvpart)
{
    const int bh = blockIdx.x, b = bh >> 3, h = bh & 7;
    const int tid = threadIdx.x;
    const int wave = tid >> 6, lane = tid & 63;
    const int l16 = lane & 15, quad = lane >> 4;
    __shared__ bf16 As[64 * 72];   // vT chunk: [e][n]
    __shared__ bf16 Bs[64 * 72];   // kT chunk: [d][n]
    const int r = tid >> 2;              // 0..63: LDS row
    const int cseg = (tid & 3) * 16;     // 16 bf16 per thread
    const size_t kRow = (size_t)(h * 64 + r) * M_;
    const size_t vRow = (size_t)(512 + h * 64 + r) * M_;

    f32x4 acc[4];
    const f32x4 z4 = { 0.f, 0.f, 0.f, 0.f };
#pragma unroll
    for (int ni = 0; ni < 4; ++ni) acc[ni] = z4;

    for (int it = 0; it < 8; ++it) {
        const size_t colBase = (size_t)b * L_ + blockIdx.y * 512 + it * 64;
        {
            const bf16* ga = kvbT + vRow + colBase + cseg;   // A = v
            const bf16* gb = kvbT + kRow + colBase + cseg;   // B = k
            *(uint4*)&As[r * 72 + cseg]     = *(const uint4*)ga;
            *(uint4*)&As[r * 72 + cseg + 8] = *(const uint4*)(ga + 8);
            *(uint4*)&Bs[r * 72 + cseg]     = *(const uint4*)gb;
            *(uint4*)&Bs[r * 72 + cseg + 8] = *(const uint4*)(gb + 8);
        }
        __syncthreads();
#pragma unroll
        for (int kk = 0; kk < 64; kk += 32) {
            bf16x8 af = *(const bf16x8*)(&As[(wave * 16 + l16) * 72 + kk + quad * 8]);
#pragma unroll
            for (int ni = 0; ni < 4; ++ni) {
                bf16x8 bfr = *(const bf16x8*)(&Bs[(ni * 16 + l16) * 72 + kk + quad * 8]);
                acc[ni] = __builtin_amdgcn_mfma_f32_16x16x32_bf16(af, bfr, acc[ni], 0, 0, 0);
            }
        }
        __syncthreads();
    }
    float* dst = kvpart + (size_t)blockIdx.y * 262144 + (size_t)bh * 4096;  // [e][d]
#pragma unroll
    for (int ni = 0; ni < 4; ++ni)
#pragma unroll
        for (int rr = 0; rr < 4; ++rr)
            dst[(wave * 16 + quad * 4 + rr) * 64 + ni * 16 + l16] = acc[ni][rr];
}

// sum 4 partials, scale by 1/L, convert to bf16 (262144 elems)
__global__ __launch_bounds__(256) void kvconv_k(
    const float* __restrict__ p, bf16* __restrict__ out)
{
    int i = blockIdx.x * 256 + threadIdx.x;
    float s = p[i] + p[i + 262144] + p[i + 2 * 262144] + p[i + 3 * 262144];
    out[i] = (bf16)(s * (1.f / (float)L_));
}

// ---------------------------------------------------------------------------
// MFMA attention: per block (bh, 64-token tile); per wave 16 tokens.
// out[n][e] = (q @ kvmatT^T)*z + lepe(v);  xamul = out * act_res.
// ---------------------------------------------------------------------------
__global__ __launch_bounds__(256) void attn_mfma_k(
    const bf16* __restrict__ q, const bf16* __restrict__ kvbT,
    const bf16* __restrict__ kvmatT, const float* __restrict__ ksum,
    const float* __restrict__ lw, const float* __restrict__ lb,
    const bf16* __restrict__ act_res, bf16* __restrict__ xa_mul)
{
    const int bh = blockIdx.x, b = bh >> 3, h = bh & 7;
    const int n0 = blockIdx.y * 64;
    const int tid = threadIdx.x;
    const int wave = tid >> 6, lane = tid & 63;
    const int l16 = lane & 15, quad = lane >> 4;

    __shared__ bf16 kvT[64 * 72];   // [e][d], stride 72 kills conflicts
    __shared__ bf16 kmS[64];

#pragma unroll
    for (int i = 0; i < 2; ++i) {
        const int idx = i * 256 + tid;               // 512 chunks of 8
        const int row = idx >> 3, col = (idx & 7) * 8;
        *(bf16x8*)&kvT[row * 72 + col] =
            *(const bf16x8*)&kvmatT[(size_t)bh * 4096 + idx * 8];
    }
    if (tid < 64) kmS[tid] = (bf16)(ksum[b * C_ + h * 64 + tid] * (1.f / (float)L_));
    __syncthreads();

    // A-frags: 16 q-rows direct from global.
    const int tok = n0 + wave * 16;
    const bf16* qbase = q + ((size_t)b * L_ + tok) * C_ + h * 64;
    const bf16x8 af0 = *(const bf16x8*)(qbase + (size_t)l16 * C_ + quad * 8);
    const bf16x8 af1 = *(const bf16x8*)(qbase + (size_t)l16 * C_ + 32 + quad * 8);

    // z-dot: B-tile col0 = k_mean
    const bf16x8 z8 = { bf16(0.f), bf16(0.f), bf16(0.f), bf16(0.f),
                        bf16(0.f), bf16(0.f), bf16(0.f), bf16(0.f) };
    const bf16x8 km0 = *(const bf16x8*)&kmS[quad * 8];
    const bf16x8 km1 = *(const bf16x8*)&kmS[32 + quad * 8];
    const bf16x8 b20 = (l16 == 0) ? km0 : z8;
    const bf16x8 b21 = (l16 == 0) ? km1 : z8;
    f32x4 zd = { 0.f, 0.f, 0.f, 0.f };
    zd = __builtin_amdgcn_mfma_f32_16x16x32_bf16(af0, b20, zd, 0, 0, 0);
    zd = __builtin_amdgcn_mfma_f32_16x16x32_bf16(af1, b21, zd, 0, 0, 0);
    float zr[4];
#pragma unroll
    for (int r = 0; r < 4; ++r)
        zr[r] = 1.f / (__shfl(zd[r], (lane & 48)) + 1e-6f);

    // q @ kvmatT^T
    f32x4 acc[4];
    const f32x4 zf4 = { 0.f, 0.f, 0.f, 0.f };
#pragma unroll
    for (int ni = 0; ni < 4; ++ni) acc[ni] = zf4;
#pragma unroll
    for (int ni = 0; ni < 4; ++ni) {
        const bf16x8 b0 = *(const bf16x8*)&kvT[(ni * 16 + l16) * 72 + quad * 8];
        const bf16x8 b1 = *(const bf16x8*)&kvT[(ni * 16 + l16) * 72 + 32 + quad * 8];
        acc[ni] = __builtin_amdgcn_mfma_f32_16x16x32_bf16(af0, b0, acc[ni], 0, 0, 0);
        acc[ni] = __builtin_amdgcn_mfma_f32_16x16x32_bf16(af1, b1, acc[ni], 0, 0, 0);
    }

    // epilogue: lane holds (token = tok+quad*4+r, e = ni*16+l16)
#pragma unroll
    for (int ni = 0; ni < 4; ++ni) {
        const int e = ni * 16 + l16;
        const int c = h * 64 + e;
        const float w0 = lw[3*c], w1 = lw[3*c+1], w2 = lw[3*c+2], lbc = lb[c];
        const bf16* vrow = kvbT + (size_t)(512 + c) * M_ + b * L_;
#pragma unroll
        for (int r = 0; r < 4; ++r) {
            const int n = tok + quad * 4 + r;
            const float v0 = (float)vrow[n];
            const float vm = (n > 0)      ? (float)vrow[n - 1] : 0.f;
            const float vp = (n < L_ - 1) ? (float)vrow[n + 1] : 0.f;
            const float lepe = vm * w0 + v0 * w1 + vp * w2 + lbc;
            const float xa = acc[ni][r] * zr[r] + lepe;
            const size_t off = ((size_t)b * L_ + n) * C_ + c;
            xa_mul[off] = (bf16)(xa * (float)act_res[off]);
        }
    }
}

// ---------------------------------------------------------------------------
// bf16 MFMA GEMM, m97 structure: global_load_lds width=16 staging, unpadded
// 128x64 LDS tiles, BM=BN=128 BK=64, 4 waves each 64x64.
// EPI: 2 elu+1->bf16, 4 gelu->bf16, 5 +res->f32, 7 kvT (row<512 elu)->bf16,
//      8 fused act/in: col<512 silu->outp, else plain->outp2 (res = 2nd bias)
// ---------------------------------------------------------------------------
template <int EPI>
__global__ __launch_bounds__(256) void gemm_bt(
    const bf16* __restrict__ A, const bf16* __restrict__ Bt,
    const float* __restrict__ bias, const float* __restrict__ res,
    void* __restrict__ outp, void* __restrict__ outp2, int K, int N)
{
    __shared__ bf16 As[128 * 64];
    __shared__ bf16 Bs[128 * 64];
    const int tid = threadIdx.x;
    const int wave = tid >> 6, lane = tid & 63;
    const int wm = (wave & 1) * 64, wn = (wave >> 1) * 64;
    const int l16 = lane & 15, quad = lane >> 4;
    const size_t tileM = (size_t)blockIdx.x * 128;
    const size_t tileN = (size_t)blockIdx.y * 128;

    const int lrow = lane >> 3;
    const int lcol = (lane & 7) * 8;

    const f32x4 z4 = { 0.f, 0.f, 0.f, 0.f };
    f32x4 acc[4][4];
#pragma unroll
    for (int mi = 0; mi < 4; ++mi)
#pragma unroll
        for (int ni = 0; ni < 4; ++ni) acc[mi][ni] = z4;

    for (int k0 = 0; k0 < K; k0 += 64) {
#pragma unroll
        for (int it = 0; it < 4; ++it) {
            const int rg = it * 32 + wave * 8;           // wave-uniform
            load_lds16(A  + (tileM + rg + lrow) * (size_t)K + k0 + lcol, As + rg * 64);
            load_lds16(Bt + (tileN + rg + lrow) * (size_t)K + k0 + lcol, Bs + rg * 64);
        }
        __syncthreads();
#pragma unroll
        for (int kk = 0; kk < 64; kk += 32) {
            bf16x8 af[4], bfr[4];
#pragma unroll
            for (int mi = 0; mi < 4; ++mi)
                af[mi] = *(const bf16x8*)(&As[(wm + mi * 16 + l16) * 64 + kk + quad * 8]);
#pragma unroll
            for (int ni = 0; ni < 4; ++ni)
                bfr[ni] = *(const bf16x8*)(&Bs[(wn + ni * 16 + l16) * 64 + kk + quad * 8]);
#pragma unroll
            for (int mi = 0; mi < 4; ++mi)
#pragma unroll
                for (int ni = 0; ni < 4; ++ni)
                    acc[mi][ni] = __builtin_amdgcn_mfma_f32_16x16x32_bf16(
                        af[mi], bfr[ni], acc[mi][ni], 0, 0, 0);
        }
        __syncthreads();
    }

#pragma unroll
    for (int mi = 0; mi < 4; ++mi) {
#pragma unroll
        for (int ni = 0; ni < 4; ++ni) {
#pragma unroll
            for (int r = 0; r < 4; ++r) {
                const size_t row = tileM + wm + mi * 16 + quad * 4 + r;
                const int   col = (int)tileN + wn + ni * 16 + l16;
                float v = acc[mi][ni][r];
                const size_t oidx = row * (size_t)N + col;
                if (EPI == 2)      ((bf16*)outp)[oidx] = (bf16)elu1f(v + bias[col]);
                else if (EPI == 4) ((bf16*)outp)[oidx] = (bf16)geluf(v + bias[col]);
                else if (EPI == 5) ((float*)outp)[oidx] = v + bias[col] + res[oidx];
                else if (EPI == 7) {
                    v += bias[(int)row];
                    ((bf16*)outp)[oidx] = (bf16)((row < 512) ? elu1f(v) : v);
                } else if (EPI == 8) {
                    const size_t orow = row * (size_t)512;
                    if (col < 512) ((bf16*)outp )[orow + col]       = (bf16)siluf(v + bias[col]);
                    else           ((bf16*)outp2)[orow + col - 512] = (bf16)(v + res[col - 512]);
                }
            }
        }
    }
}

// ---------------------------------------------------------------------------
// workspace layout (bytes) — total 125,845,504 (~120 MiB)
// ---------------------------------------------------------------------------
#define OFF_WT_ACTIN ((size_t)0)         // bf16 [1024][512] 1MB
#define OFF_WT_Q    ((size_t)1048576)
#define OFF_WT_KV   ((size_t)1572864)
#define OFF_WT_OUT  ((size_t)2621440)
#define OFF_WT_FC1  ((size_t)3145728)
#define OFF_WT_FC2  ((size_t)5242880)
#define OFF_XLN     ((size_t)7340032)    // bf16 16MB (xqb, kvbf, hln alias)
#define OFF_ACTRES  ((size_t)24117248)   // bf16 16MB (x3 aliases from here)
#define OFF_Y       ((size_t)40894464)   // bf16 16MB (qb aliases)
#define OFF_XP      ((size_t)57671680)   // bf16 16MB (kvpart, h1 alias from here)
#define OFF_KV      ((size_t)74448896)   // bf16 32MB  kvbT [1024][16384]
#define OFF_KSUM    ((size_t)108003328)  // f32 16KB
#define OFF_KVMAT   ((size_t)108019712)  // f32 1MB (unused now)
#define OFF_XAMUL   ((size_t)109068288)  // bf16 16MB  -> end 125845504
#define OFF_X3      ((size_t)24117248)   // f32 32MB over actres+Y (dead)
#define OFF_H1      ((size_t)57671680)   // bf16 64MB over xp+kv+kvmat+xamul (dead)
#define WS_REQUIRED ((size_t)125845504)

extern "C" void kernel_launch(void* const* d_in, const int* in_sizes, int n_in,
                              void* d_out, int out_size, void* d_ws, size_t ws_size,
                              hipStream_t stream)
{
    const float* x_q    = (const float*)d_in[0];
    const float* x_kv   = (const float*)d_in[1];
    const float* cpe1_w = (const float*)d_in[2];
    const float* cpe1_b = (const float*)d_in[3];
    const float* n1_g   = (const float*)d_in[4];
    const float* n1_b   = (const float*)d_in[5];
    const float* in_w   = (const float*)d_in[6];
    const float* in_b   = (const float*)d_in[7];
    const float* act_w  = (const float*)d_in[8];
    const float* act_b  = (const float*)d_in[9];
    const float* dwc_w  = (const float*)d_in[10];
    const float* dwc_b  = (const float*)d_in[11];
    const float* q_w    = (const float*)d_in[12];
    const float* q_b    = (const float*)d_in[13];
    const float* kv_w   = (const float*)d_in[14];
    const float* kv_b   = (const float*)d_in[15];
    const float* lepe_w = (const float*)d_in[16];
    const float* lepe_b = (const float*)d_in[17];
    const float* out_w  = (const float*)d_in[18];
    const float* out_b  = (const float*)d_in[19];
    const float* cpe2_w = (const float*)d_in[20];
    const float* cpe2_b = (const float*)d_in[21];
    const float* n2_g   = (const float*)d_in[22];
    const float* n2_b   = (const float*)d_in[23];
    const float* fc1_w  = (const float*)d_in[24];
    const float* fc1_b  = (const float*)d_in[25];
    const float* fc2_w  = (const float*)d_in[26];
    const float* fc2_b  = (const float*)d_in[27];

    float* outf = (float*)d_out;

    if (ws_size < WS_REQUIRED) {
        zero_k<<<(out_size + 255) / 256, 256, 0, stream>>>(outf, out_size);
        ws_diag_k<<<1, 64, 0, stream>>>(outf, (float)ws_size);
        return;
    }

    char* ws = (char*)d_ws;
    bf16*  wt_actin = (bf16*)(ws + OFF_WT_ACTIN);
    bf16*  wt_q   = (bf16*)(ws + OFF_WT_Q);
    bf16*  wt_kv  = (bf16*)(ws + OFF_WT_KV);
    bf16*  wt_out = (bf16*)(ws + OFF_WT_OUT);
    bf16*  wt_fc1 = (bf16*)(ws + OFF_WT_FC1);
    bf16*  wt_fc2 = (bf16*)(ws + OFF_WT_FC2);
    bf16*  xln    = (bf16*)(ws + OFF_XLN);
    bf16*  xqb    = (bf16*)(ws + OFF_XLN);      // alias: xln dead after act/in
    bf16*  kvbf   = (bf16*)(ws + OFF_XLN);      // alias: xqb dead after q-gemm
    bf16*  hln    = (bf16*)(ws + OFF_XLN);      // alias: kvbf dead after attn
    bf16*  actres = (bf16*)(ws + OFF_ACTRES);
    bf16*  Y      = (bf16*)(ws + OFF_Y);
    bf16*  qb     = (bf16*)(ws + OFF_Y);        // alias: Y dead after dwc
    bf16*  xp     = (bf16*)(ws + OFF_XP);
    float* kvpart = (float*)(ws + OFF_XP);      // alias: xp dead after kv-gemm (4MB)
    bf16*  kvbT   = (bf16*)(ws + OFF_KV);       // [1024][16384]
    float* ksum   = (float*)(ws + OFF_KSUM);
    bf16*  xamul  = (bf16*)(ws + OFF_XAMUL);
    float* x3     = (float*)(ws + OFF_X3);      // alias
    bf16*  h1     = (bf16*)(ws + OFF_H1);       // alias

    // weight convert + transpose (W KxN -> Wt NxK bf16)
    transpose_bf16_k<<<dim3(16, 16), 256, 0, stream>>>(act_w, wt_actin, 512, 512);
    transpose_bf16_k<<<dim3(16, 16), 256, 0, stream>>>(in_w,  wt_actin + 512 * 512, 512, 512);
    transpose_bf16_k<<<dim3(16, 16), 256, 0, stream>>>(q_w,   wt_q,   512, 512);
    transpose_bf16_k<<<dim3(32, 16), 256, 0, stream>>>(kv_w,  wt_kv,  512, 1024);
    transpose_bf16_k<<<dim3(16, 16), 256, 0, stream>>>(out_w, wt_out, 512, 512);
    transpose_bf16_k<<<dim3(64, 16), 256, 0, stream>>>(fc1_w, wt_fc1, 512, 2048);
    transpose_bf16_k<<<dim3(16, 64), 256, 0, stream>>>(fc2_w, wt_fc2, 2048, 512);

    // cpe1 + LN1: shortcut (fp32) lives in d_out
    cpe_ln_k<<<M_, 256, 0, stream>>>(x_kv, cpe1_w, cpe1_b, n1_g, n1_b, outf, xln);

    // fused act gate + in-proj (one pass over xln), N=1024
    gemm_bt<8><<<dim3(128, 8), 256, 0, stream>>>(xln, wt_actin, act_b, in_b, actres, Y, 512, 1024);

    // flat-reshape dwconv + silu -> xp (frees Y)
    dwc_silu_k<<<32768, 256, 0, stream>>>(Y, dwc_w, dwc_b, xp);

    // x_q -> bf16 (into dead xln region), then q = elu+1(xqb @ q_w) -> qb (@Y)
    f32_to_bf16_k<<<8192, 256, 0, stream>>>(x_q, xqb, M_ * C_ / 4);
    gemm_bt<2><<<dim3(128, 4), 256, 0, stream>>>(xqb, wt_q, q_b, nullptr, qb, nullptr, 512, 512);

    // kvbT[c][token] = (xp @ kv_w)^T : roles swapped (A=wt_kv, Bt=xp)
    gemm_bt<7><<<dim3(8, 128), 256, 0, stream>>>(wt_kv, xp, kv_b, nullptr, kvbT, nullptr, 512, M_);

    // k_mean, kvmatT partials (MFMA, no atomics), reduce+bf16 convert
    ksum_k<<<C_, 256, 0, stream>>>(kvbT, ksum);
    kvmat_mfma_k<<<dim3(64, 4), 256, 0, stream>>>(kvbT, kvpart);
    kvconv_k<<<1024, 256, 0, stream>>>(kvpart, kvbf);

    // MFMA attention + lepe + gate multiply
    attn_mfma_k<<<dim3(64, 32), 256, 0, stream>>>(qb, kvbT, kvbf, ksum,
                                                  lepe_w, lepe_b, actres, xamul);

    // out-proj + shortcut residual, in-place on d_out
    gemm_bt<5><<<dim3(128, 4), 256, 0, stream>>>(xamul, wt_out, out_b, outf, outf, nullptr, 512, 512);

    // cpe2 + LN2: x2 (=d_out) -> x3 (fp32 ws) + hln (bf16)
    cpe_ln_k<<<M_, 256, 0, stream>>>(outf, cpe2_w, cpe2_b, n2_g, n2_b, x3, hln);

    // MLP: fc1 (gelu) -> fc2 (+x3) -> d_out
    gemm_bt<4><<<dim3(128, 16), 256, 0, stream>>>(hln, wt_fc1, fc1_b, nullptr, h1, nullptr, 512, 2048);
    gemm_bt<5><<<dim3(128, 4),  256, 0, stream>>>(h1,  wt_fc2, fc2_b, x3, outf, nullptr, 2048, 512);

    (void)in_sizes; (void)n_in; (void)out_size; (void)ws_size;
}

// Round 7
// 512.030 us; speedup vs baseline: 1.2097x; 1.0722x over previous
//
#include <hip/hip_runtime.h>
#include <cmath>

// ---------------------------------------------------------------------------
// MLLA block, B=8 L=2048 C=512 H=8 HD=64 MLP_H=2048, fp32 I/O, bf16 MFMA GEMMs
// R7: XOR-swizzled LDS tiles in gemm_bt (16-way bank conflict -> 2-way free);
//     3-term A&S erf; single merged weight-transpose launch.
// ---------------------------------------------------------------------------

typedef __bf16 bf16;
typedef __bf16 bf16x8 __attribute__((ext_vector_type(8)));
typedef __bf16 bf16x4 __attribute__((ext_vector_type(4)));
typedef float  f32x4  __attribute__((ext_vector_type(4)));

#define B_  8
#define L_  2048
#define C_  512
#define M_  (B_ * L_)          // 16384 tokens

__device__ __forceinline__ float siluf(float x) { return x / (1.f + __expf(-x)); }
__device__ __forceinline__ float elu1f(float x) { return x > 0.f ? x + 1.f : __expf(x); }

// exact-GELU via Abramowitz-Stegun 7.1.25 erf (3-term, |eps| <= 2.5e-5)
__device__ __forceinline__ float geluf(float x)
{
    const float z = fabsf(x) * 0.70710678118654752f;
    const float t = __frcp_rn(1.f + 0.47047f * z);
    const float poly = t * (0.3480242f + t * (-0.0958798f + t * 0.7478556f));
    const float erfz = 1.f - poly * __expf(-z * z);
    const float erfs = (x < 0.f) ? -erfz : erfz;
    return 0.5f * x * (1.f + erfs);
}

// global -> LDS direct DMA, 16B per lane. lds dest must be wave-uniform base;
// HW deposits lane i at base + i*16B.
__device__ __forceinline__ void load_lds16(const bf16* g, bf16* l)
{
    __builtin_amdgcn_global_load_lds(
        (const __attribute__((address_space(1))) void*)g,
        (__attribute__((address_space(3))) void*)l, 16, 0, 0);
}

// ---------------------------------------------------------------------------
__global__ __launch_bounds__(256) void zero_k(float* __restrict__ p, int n)
{
    int i = blockIdx.x * 256 + threadIdx.x;
    if (i < n) p[i] = 0.f;
}

__global__ __launch_bounds__(64) void ws_diag_k(float* __restrict__ out, float v)
{
    if (threadIdx.x == 0 && blockIdx.x == 0) out[0] = v;
}

// ---------------------------------------------------------------------------
// fp32 -> bf16 elementwise (vectorized x4)
// ---------------------------------------------------------------------------
__global__ __launch_bounds__(256) void f32_to_bf16_k(
    const float* __restrict__ in, bf16* __restrict__ out, int n4)
{
    int i = blockIdx.x * 256 + threadIdx.x;
    if (i >= n4) return;
    float4 v = ((const float4*)in)[i];
    bf16x4 o = { (bf16)v.x, (bf16)v.y, (bf16)v.z, (bf16)v.w };
    ((bf16x4*)out)[i] = o;
}

// ---------------------------------------------------------------------------
// ALL weight transposes in one launch. fp32 (K x N) -> bf16 (N x K).
// ---------------------------------------------------------------------------
struct TJob  { const float* W; bf16* Wt; int K; int N; int blk0; };
struct TJobs { TJob j[7]; };

__global__ __launch_bounds__(256) void transpose_all_k(TJobs jobs)
{
    __shared__ float tile[32][33];
    const int bid = blockIdx.x;
    int ji = 0;
#pragma unroll
    for (int i = 1; i < 7; ++i) if (bid >= jobs.j[i].blk0) ji = i;
    const float* W  = jobs.j[ji].W;
    bf16*        Wt = jobs.j[ji].Wt;
    const int K = jobs.j[ji].K, N = jobs.j[ji].N;
    const int rel = bid - jobs.j[ji].blk0;
    const int nb = N >> 5;
    const int n0 = (rel % nb) * 32, k0 = (rel / nb) * 32;
    const int tx = threadIdx.x & 31, ty = threadIdx.x >> 5;   // 32 x 8
#pragma unroll
    for (int i = 0; i < 32; i += 8)
        tile[ty + i][tx] = W[(size_t)(k0 + ty + i) * N + n0 + tx];
    __syncthreads();
#pragma unroll
    for (int i = 0; i < 32; i += 8)
        Wt[(size_t)(n0 + ty + i) * K + k0 + tx] = (bf16)tile[tx][ty + i];
}

// ---------------------------------------------------------------------------
// depthwise conv (k=3, zero pad) along L + residual + LayerNorm.
// ---------------------------------------------------------------------------
__global__ __launch_bounds__(256) void cpe_ln_k(
    const float* __restrict__ xin, const float* __restrict__ cw,
    const float* __restrict__ cb, const float* __restrict__ g,
    const float* __restrict__ bb, float* __restrict__ xres,
    bf16* __restrict__ xln)
{
    const int token = blockIdx.x;
    const int l = token & (L_ - 1);
    const int tid = threadIdx.x;
    const float* row = xin + (size_t)token * C_;
    float v[2]; float s = 0.f, s2 = 0.f;
#pragma unroll
    for (int i = 0; i < 2; ++i) {
        const int c = tid + i * 256;
        float x0 = row[c];
        float xm = (l > 0)      ? row[c - C_] : 0.f;
        float xp = (l < L_ - 1) ? row[c + C_] : 0.f;
        float t = x0 + xm * cw[3*c] + x0 * cw[3*c+1] + xp * cw[3*c+2] + cb[c];
        v[i] = t; s += t; s2 += t * t;
    }
#pragma unroll
    for (int off = 32; off; off >>= 1) { s += __shfl_down(s, off); s2 += __shfl_down(s2, off); }
    __shared__ float rs[4], rs2[4];
    if ((tid & 63) == 0) { rs[tid >> 6] = s; rs2[tid >> 6] = s2; }
    __syncthreads();
    s  = rs[0] + rs[1] + rs[2] + rs[3];
    s2 = rs2[0] + rs2[1] + rs2[2] + rs2[3];
    const float mu = s * (1.f / C_);
    const float rstd = rsqrtf(s2 * (1.f / C_) - mu * mu + 1e-5f);
    float* orow = xres + (size_t)token * C_;
    bf16*  lrow = xln  + (size_t)token * C_;
#pragma unroll
    for (int i = 0; i < 2; ++i) {
        const int c = tid + i * 256;
        orow[c] = v[i];
        lrow[c] = (bf16)((v[i] - mu) * rstd * g[c] + bb[c]);
    }
}

// ---------------------------------------------------------------------------
// dwc conv over the (b,c,l)-reinterpreted flat buffer + SiLU.
// ---------------------------------------------------------------------------
__global__ __launch_bounds__(256) void dwc_silu_k(
    const bf16* __restrict__ Y, const float* __restrict__ w,
    const float* __restrict__ b, bf16* __restrict__ xp)
{
    const size_t idx = (size_t)blockIdx.x * 256 + threadIdx.x;   // over B_*L_*C_
    const int m = (int)(idx & (size_t)(L_ * C_ - 1));
    const int ch = m >> 11;          // m / 2048
    const int pos = m & (L_ - 1);
    float x0 = (float)Y[idx];
    float xm = (pos > 0)      ? (float)Y[idx - 1] : 0.f;
    float xq = (pos < L_ - 1) ? (float)Y[idx + 1] : 0.f;
    float t = xm * w[3*ch] + x0 * w[3*ch+1] + xq * w[3*ch+2] + b[ch];
    xp[idx] = (bf16)siluf(t);
}

// ---------------------------------------------------------------------------
// ksum[b, c] = sum_n k[b,n,c] from kvbT rows (c-major): contiguous reduction.
// ---------------------------------------------------------------------------
__global__ __launch_bounds__(256) void ksum_k(
    const bf16* __restrict__ kvbT, float* __restrict__ ksum)
{
    const int c = blockIdx.x;
    const int wave = threadIdx.x >> 6, lane = threadIdx.x & 63;
#pragma unroll
    for (int i = 0; i < 2; ++i) {
        const int b = wave + i * 4;
        const bf16* src = kvbT + (size_t)c * M_ + b * L_ + lane * 32;
        float s = 0.f;
#pragma unroll
        for (int u = 0; u < 4; ++u) {
            bf16x8 v = *(const bf16x8*)(src + u * 8);
#pragma unroll
            for (int j = 0; j < 8; ++j) s += (float)v[j];
        }
#pragma unroll
        for (int o = 32; o; o >>= 1) s += __shfl_down(s, o);
        if (lane == 0) ksum[b * C_ + c] = s;
    }
}

// ---------------------------------------------------------------------------
// kvpart[split][b,h,e,d] = sum_{n in split} v[b,n,h,e] * k[b,n,h,d]
// via MFMA (transposed layout [e][d]); plain stores, no atomics.
// ---------------------------------------------------------------------------
__global__ __launch_bounds__(256) void kvmat_mfma_k(
    const bf16* __restrict__ kvbT, float* __restrict__ kvpart)
{
    const int bh = blockIdx.x, b = bh >> 3, h = bh & 7;
    const int tid = threadIdx.x;
    const int wave = tid >> 6, lane = tid & 63;
    const int l16 = lane & 15, quad = lane >> 4;
    __shared__ bf16 As[64 * 72];   // vT chunk: [e][n]
    __shared__ bf16 Bs[64 * 72];   // kT chunk: [d][n]
    const int r = tid >> 2;              // 0..63: LDS row
    const int cseg = (tid & 3) * 16;     // 16 bf16 per thread
    const size_t kRow = (size_t)(h * 64 + r) * M_;
    const size_t vRow = (size_t)(512 + h * 64 + r) * M_;

    f32x4 acc[4];
    const f32x4 z4 = { 0.f, 0.f, 0.f, 0.f };
#pragma unroll
    for (int ni = 0; ni < 4; ++ni) acc[ni] = z4;

    for (int it = 0; it < 8; ++it) {
        const size_t colBase = (size_t)b * L_ + blockIdx.y * 512 + it * 64;
        {
            const bf16* ga = kvbT + vRow + colBase + cseg;   // A = v
            const bf16* gb = kvbT + kRow + colBase + cseg;   // B = k
            *(uint4*)&As[r * 72 + cseg]     = *(const uint4*)ga;
            *(uint4*)&As[r * 72 + cseg + 8] = *(const uint4*)(ga + 8);
            *(uint4*)&Bs[r * 72 + cseg]     = *(const uint4*)gb;
            *(uint4*)&Bs[r * 72 + cseg + 8] = *(const uint4*)(gb + 8);
        }
        __syncthreads();
#pragma unroll
        for (int kk = 0; kk < 64; kk += 32) {
            bf16x8 af = *(const bf16x8*)(&As[(wave * 16 + l16) * 72 + kk + quad * 8]);
#pragma unroll
            for (int ni = 0; ni < 4; ++ni) {
                bf16x8 bfr = *(const bf16x8*)(&Bs[(ni * 16 + l16) * 72 + kk + quad * 8]);
                acc[ni] = __builtin_amdgcn_mfma_f32_16x16x32_bf16(af, bfr, acc[ni], 0, 0, 0);
            }
        }
        __syncthreads();
    }
    float* dst = kvpart + (size_t)blockIdx.y * 262144 + (size_t)bh * 4096;  // [e][d]
#pragma unroll
    for (int ni = 0; ni < 4; ++ni)
#pragma unroll
        for (int rr = 0; rr < 4; ++rr)
            dst[(wave * 16 + quad * 4 + rr) * 64 + ni * 16 + l16] = acc[ni][rr];
}

// sum 4 partials, scale by 1/L, convert to bf16 (262144 elems)
__global__ __launch_bounds__(256) void kvconv_k(
    const float* __restrict__ p, bf16* __restrict__ out)
{
    int i = blockIdx.x * 256 + threadIdx.x;
    float s = p[i] + p[i + 262144] + p[i + 2 * 262144] + p[i + 3 * 262144];
    out[i] = (bf16)(s * (1.f / (float)L_));
}

// ---------------------------------------------------------------------------
// MFMA attention: per block (bh, 64-token tile); per wave 16 tokens.
// out[n][e] = (q @ kvmatT^T)*z + lepe(v);  xamul = out * act_res.
// ---------------------------------------------------------------------------
__global__ __launch_bounds__(256) void attn_mfma_k(
    const bf16* __restrict__ q, const bf16* __restrict__ kvbT,
    const bf16* __restrict__ kvmatT, const float* __restrict__ ksum,
    const float* __restrict__ lw, const float* __restrict__ lb,
    const bf16* __restrict__ act_res, bf16* __restrict__ xa_mul)
{
    const int bh = blockIdx.x, b = bh >> 3, h = bh & 7;
    const int n0 = blockIdx.y * 64;
    const int tid = threadIdx.x;
    const int wave = tid >> 6, lane = tid & 63;
    const int l16 = lane & 15, quad = lane >> 4;

    __shared__ bf16 kvT[64 * 72];   // [e][d], stride 72 -> 2-way only
    __shared__ bf16 kmS[64];

#pragma unroll
    for (int i = 0; i < 2; ++i) {
        const int idx = i * 256 + tid;               // 512 chunks of 8
        const int row = idx >> 3, col = (idx & 7) * 8;
        *(bf16x8*)&kvT[row * 72 + col] =
            *(const bf16x8*)&kvmatT[(size_t)bh * 4096 + idx * 8];
    }
    if (tid < 64) kmS[tid] = (bf16)(ksum[b * C_ + h * 64 + tid] * (1.f / (float)L_));
    __syncthreads();

    // A-frags: 16 q-rows direct from global.
    const int tok = n0 + wave * 16;
    const bf16* qbase = q + ((size_t)b * L_ + tok) * C_ + h * 64;
    const bf16x8 af0 = *(const bf16x8*)(qbase + (size_t)l16 * C_ + quad * 8);
    const bf16x8 af1 = *(const bf16x8*)(qbase + (size_t)l16 * C_ + 32 + quad * 8);

    // z-dot: B-tile col0 = k_mean
    const bf16x8 z8 = { bf16(0.f), bf16(0.f), bf16(0.f), bf16(0.f),
                        bf16(0.f), bf16(0.f), bf16(0.f), bf16(0.f) };
    const bf16x8 km0 = *(const bf16x8*)&kmS[quad * 8];
    const bf16x8 km1 = *(const bf16x8*)&kmS[32 + quad * 8];
    const bf16x8 b20 = (l16 == 0) ? km0 : z8;
    const bf16x8 b21 = (l16 == 0) ? km1 : z8;
    f32x4 zd = { 0.f, 0.f, 0.f, 0.f };
    zd = __builtin_amdgcn_mfma_f32_16x16x32_bf16(af0, b20, zd, 0, 0, 0);
    zd = __builtin_amdgcn_mfma_f32_16x16x32_bf16(af1, b21, zd, 0, 0, 0);
    float zr[4];
#pragma unroll
    for (int r = 0; r < 4; ++r)
        zr[r] = 1.f / (__shfl(zd[r], (lane & 48)) + 1e-6f);

    // q @ kvmatT^T
    f32x4 acc[4];
    const f32x4 zf4 = { 0.f, 0.f, 0.f, 0.f };
#pragma unroll
    for (int ni = 0; ni < 4; ++ni) acc[ni] = zf4;
#pragma unroll
    for (int ni = 0; ni < 4; ++ni) {
        const bf16x8 b0 = *(const bf16x8*)&kvT[(ni * 16 + l16) * 72 + quad * 8];
        const bf16x8 b1 = *(const bf16x8*)&kvT[(ni * 16 + l16) * 72 + 32 + quad * 8];
        acc[ni] = __builtin_amdgcn_mfma_f32_16x16x32_bf16(af0, b0, acc[ni], 0, 0, 0);
        acc[ni] = __builtin_amdgcn_mfma_f32_16x16x32_bf16(af1, b1, acc[ni], 0, 0, 0);
    }

    // epilogue: lane holds (token = tok+quad*4+r, e = ni*16+l16)
#pragma unroll
    for (int ni = 0; ni < 4; ++ni) {
        const int e = ni * 16 + l16;
        const int c = h * 64 + e;
        const float w0 = lw[3*c], w1 = lw[3*c+1], w2 = lw[3*c+2], lbc = lb[c];
        const bf16* vrow = kvbT + (size_t)(512 + c) * M_ + b * L_;
#pragma unroll
        for (int r = 0; r < 4; ++r) {
            const int n = tok + quad * 4 + r;
            const float v0 = (float)vrow[n];
            const float vm = (n > 0)      ? (float)vrow[n - 1] : 0.f;
            const float vp = (n < L_ - 1) ? (float)vrow[n + 1] : 0.f;
            const float lepe = vm * w0 + v0 * w1 + vp * w2 + lbc;
            const float xa = acc[ni][r] * zr[r] + lepe;
            const size_t off = ((size_t)b * L_ + n) * C_ + c;
            xa_mul[off] = (bf16)(xa * (float)act_res[off]);
        }
    }
}

// ---------------------------------------------------------------------------
// bf16 MFMA GEMM, m97 structure + XOR-swizzled LDS tiles.
// Lane i stages global col-block ((i&7)^(lrow&7)) into LDS slot (i&7): the
// fragment read then hits 8 distinct bank-groups (2-way only, free).
// EPI: 2 elu+1->bf16, 4 gelu->bf16, 5 +res->f32, 7 kvT (row<512 elu)->bf16,
//      8 fused act/in: col<512 silu->outp, else plain->outp2
// ---------------------------------------------------------------------------
template <int EPI>
__global__ __launch_bounds__(256) void gemm_bt(
    const bf16* __restrict__ A, const bf16* __restrict__ Bt,
    const float* __restrict__ bias, const float* __restrict__ res,
    void* __restrict__ outp, void* __restrict__ outp2, int K, int N)
{
    __shared__ bf16 As[128 * 64];
    __shared__ bf16 Bs[128 * 64];
    const int tid = threadIdx.x;
    const int wave = tid >> 6, lane = tid & 63;
    const int wm = (wave & 1) * 64, wn = (wave >> 1) * 64;
    const int l16 = lane & 15, quad = lane >> 4;
    const size_t tileM = (size_t)blockIdx.x * 128;
    const size_t tileN = (size_t)blockIdx.y * 128;

    const int lrow = lane >> 3;
    const int lcol = (((lane & 7) ^ (lrow & 7))) * 8;   // swizzled source col
    const int swz  = l16 & 7;                           // read-side XOR

    const f32x4 z4 = { 0.f, 0.f, 0.f, 0.f };
    f32x4 acc[4][4];
#pragma unroll
    for (int mi = 0; mi < 4; ++mi)
#pragma unroll
        for (int ni = 0; ni < 4; ++ni) acc[mi][ni] = z4;

    for (int k0 = 0; k0 < K; k0 += 64) {
#pragma unroll
        for (int it = 0; it < 4; ++it) {
            const int rg = it * 32 + wave * 8;           // wave-uniform (mult of 8)
            load_lds16(A  + (tileM + rg + lrow) * (size_t)K + k0 + lcol, As + rg * 64);
            load_lds16(Bt + (tileN + rg + lrow) * (size_t)K + k0 + lcol, Bs + rg * 64);
        }
        __syncthreads();
#pragma unroll
        for (int kk = 0; kk < 64; kk += 32) {
            bf16x8 af[4], bfr[4];
#pragma unroll
            for (int mi = 0; mi < 4; ++mi)
                af[mi] = *(const bf16x8*)(&As[(wm + mi * 16 + l16) * 64
                                              + ((((kk >> 3) + quad) ^ swz) * 8)]);
#pragma unroll
            for (int ni = 0; ni < 4; ++ni)
                bfr[ni] = *(const bf16x8*)(&Bs[(wn + ni * 16 + l16) * 64
                                               + ((((kk >> 3) + quad) ^ swz) * 8)]);
#pragma unroll
            for (int mi = 0; mi < 4; ++mi)
#pragma unroll
                for (int ni = 0; ni < 4; ++ni)
                    acc[mi][ni] = __builtin_amdgcn_mfma_f32_16x16x32_bf16(
                        af[mi], bfr[ni], acc[mi][ni], 0, 0, 0);
        }
        __syncthreads();
    }

#pragma unroll
    for (int mi = 0; mi < 4; ++mi) {
#pragma unroll
        for (int ni = 0; ni < 4; ++ni) {
#pragma unroll
            for (int r = 0; r < 4; ++r) {
                const size_t row = tileM + wm + mi * 16 + quad * 4 + r;
                const int   col = (int)tileN + wn + ni * 16 + l16;
                float v = acc[mi][ni][r];
                const size_t oidx = row * (size_t)N + col;
                if (EPI == 2)      ((bf16*)outp)[oidx] = (bf16)elu1f(v + bias[col]);
                else if (EPI == 4) ((bf16*)outp)[oidx] = (bf16)geluf(v + bias[col]);
                else if (EPI == 5) ((float*)outp)[oidx] = v + bias[col] + res[oidx];
                else if (EPI == 7) {
                    v += bias[(int)row];
                    ((bf16*)outp)[oidx] = (bf16)((row < 512) ? elu1f(v) : v);
                } else if (EPI == 8) {
                    const size_t orow = row * (size_t)512;
                    if (col < 512) ((bf16*)outp )[orow + col]       = (bf16)siluf(v + bias[col]);
                    else           ((bf16*)outp2)[orow + col - 512] = (bf16)(v + res[col - 512]);
                }
            }
        }
    }
}

// ---------------------------------------------------------------------------
// workspace layout (bytes) — total 125,845,504 (~120 MiB)
// ---------------------------------------------------------------------------
#define OFF_WT_ACTIN ((size_t)0)         // bf16 [1024][512] 1MB
#define OFF_WT_Q    ((size_t)1048576)
#define OFF_WT_KV   ((size_t)1572864)
#define OFF_WT_OUT  ((size_t)2621440)
#define OFF_WT_FC1  ((size_t)3145728)
#define OFF_WT_FC2  ((size_t)5242880)
#define OFF_XLN     ((size_t)7340032)    // bf16 16MB (xqb, kvbf, hln alias)
#define OFF_ACTRES  ((size_t)24117248)   // bf16 16MB (x3 aliases from here)
#define OFF_Y       ((size_t)40894464)   // bf16 16MB (qb aliases)
#define OFF_XP      ((size_t)57671680)   // bf16 16MB (kvpart, h1 alias from here)
#define OFF_KV      ((size_t)74448896)   // bf16 32MB  kvbT [1024][16384]
#define OFF_KSUM    ((size_t)108003328)  // f32 16KB
#define OFF_XAMUL   ((size_t)109068288)  // bf16 16MB  -> end 125845504
#define OFF_X3      ((size_t)24117248)   // f32 32MB over actres+Y (dead)
#define OFF_H1      ((size_t)57671680)   // bf16 64MB over xp+kv+xamul (dead)
#define WS_REQUIRED ((size_t)125845504)

extern "C" void kernel_launch(void* const* d_in, const int* in_sizes, int n_in,
                              void* d_out, int out_size, void* d_ws, size_t ws_size,
                              hipStream_t stream)
{
    const float* x_q    = (const float*)d_in[0];
    const float* x_kv   = (const float*)d_in[1];
    const float* cpe1_w = (const float*)d_in[2];
    const float* cpe1_b = (const float*)d_in[3];
    const float* n1_g   = (const float*)d_in[4];
    const float* n1_b   = (const float*)d_in[5];
    const float* in_w   = (const float*)d_in[6];
    const float* in_b   = (const float*)d_in[7];
    const float* act_w  = (const float*)d_in[8];
    const float* act_b  = (const float*)d_in[9];
    const float* dwc_w  = (const float*)d_in[10];
    const float* dwc_b  = (const float*)d_in[11];
    const float* q_w    = (const float*)d_in[12];
    const float* q_b    = (const float*)d_in[13];
    const float* kv_w   = (const float*)d_in[14];
    const float* kv_b   = (const float*)d_in[15];
    const float* lepe_w = (const float*)d_in[16];
    const float* lepe_b = (const float*)d_in[17];
    const float* out_w  = (const float*)d_in[18];
    const float* out_b  = (const float*)d_in[19];
    const float* cpe2_w = (const float*)d_in[20];
    const float* cpe2_b = (const float*)d_in[21];
    const float* n2_g   = (const float*)d_in[22];
    const float* n2_b   = (const float*)d_in[23];
    const float* fc1_w  = (const float*)d_in[24];
    const float* fc1_b  = (const float*)d_in[25];
    const float* fc2_w  = (const float*)d_in[26];
    const float* fc2_b  = (const float*)d_in[27];

    float* outf = (float*)d_out;

    if (ws_size < WS_REQUIRED) {
        zero_k<<<(out_size + 255) / 256, 256, 0, stream>>>(outf, out_size);
        ws_diag_k<<<1, 64, 0, stream>>>(outf, (float)ws_size);
        return;
    }

    char* ws = (char*)d_ws;
    bf16*  wt_actin = (bf16*)(ws + OFF_WT_ACTIN);
    bf16*  wt_q   = (bf16*)(ws + OFF_WT_Q);
    bf16*  wt_kv  = (bf16*)(ws + OFF_WT_KV);
    bf16*  wt_out = (bf16*)(ws + OFF_WT_OUT);
    bf16*  wt_fc1 = (bf16*)(ws + OFF_WT_FC1);
    bf16*  wt_fc2 = (bf16*)(ws + OFF_WT_FC2);
    bf16*  xln    = (bf16*)(ws + OFF_XLN);
    bf16*  xqb    = (bf16*)(ws + OFF_XLN);      // alias: xln dead after act/in
    bf16*  kvbf   = (bf16*)(ws + OFF_XLN);      // alias: xqb dead after q-gemm
    bf16*  hln    = (bf16*)(ws + OFF_XLN);      // alias: kvbf dead after attn
    bf16*  actres = (bf16*)(ws + OFF_ACTRES);
    bf16*  Y      = (bf16*)(ws + OFF_Y);
    bf16*  qb     = (bf16*)(ws + OFF_Y);        // alias: Y dead after dwc
    bf16*  xp     = (bf16*)(ws + OFF_XP);
    float* kvpart = (float*)(ws + OFF_XP);      // alias: xp dead after kv-gemm (4MB)
    bf16*  kvbT   = (bf16*)(ws + OFF_KV);       // [1024][16384]
    float* ksum   = (float*)(ws + OFF_KSUM);
    bf16*  xamul  = (bf16*)(ws + OFF_XAMUL);
    float* x3     = (float*)(ws + OFF_X3);      // alias
    bf16*  h1     = (bf16*)(ws + OFF_H1);       // alias

    // all weight transposes in one launch
    TJobs jobs;
    jobs.j[0] = { act_w, wt_actin,             512,  512,    0 };
    jobs.j[1] = { in_w,  wt_actin + 512 * 512, 512,  512,  256 };
    jobs.j[2] = { q_w,   wt_q,                 512,  512,  512 };
    jobs.j[3] = { kv_w,  wt_kv,                512, 1024,  768 };
    jobs.j[4] = { out_w, wt_out,               512,  512, 1280 };
    jobs.j[5] = { fc1_w, wt_fc1,               512, 2048, 1536 };
    jobs.j[6] = { fc2_w, wt_fc2,              2048,  512, 2560 };
    transpose_all_k<<<3584, 256, 0, stream>>>(jobs);

    // cpe1 + LN1: shortcut (fp32) lives in d_out
    cpe_ln_k<<<M_, 256, 0, stream>>>(x_kv, cpe1_w, cpe1_b, n1_g, n1_b, outf, xln);

    // fused act gate + in-proj (one pass over xln), N=1024
    gemm_bt<8><<<dim3(128, 8), 256, 0, stream>>>(xln, wt_actin, act_b, in_b, actres, Y, 512, 1024);

    // flat-reshape dwconv + silu -> xp (frees Y)
    dwc_silu_k<<<32768, 256, 0, stream>>>(Y, dwc_w, dwc_b, xp);

    // x_q -> bf16 (into dead xln region), then q = elu+1(xqb @ q_w) -> qb (@Y)
    f32_to_bf16_k<<<8192, 256, 0, stream>>>(x_q, xqb, M_ * C_ / 4);
    gemm_bt<2><<<dim3(128, 4), 256, 0, stream>>>(xqb, wt_q, q_b, nullptr, qb, nullptr, 512, 512);

    // kvbT[c][token] = (xp @ kv_w)^T : roles swapped (A=wt_kv, Bt=xp)
    gemm_bt<7><<<dim3(8, 128), 256, 0, stream>>>(wt_kv, xp, kv_b, nullptr, kvbT, nullptr, 512, M_);

    // k_mean, kvmatT partials (MFMA, no atomics), reduce+bf16 convert
    ksum_k<<<C_, 256, 0, stream>>>(kvbT, ksum);
    kvmat_mfma_k<<<dim3(64, 4), 256, 0, stream>>>(kvbT, kvpart);
    kvconv_k<<<1024, 256, 0, stream>>>(kvpart, kvbf);

    // MFMA attention + lepe + gate multiply
    attn_mfma_k<<<dim3(64, 32), 256, 0, stream>>>(qb, kvbT, kvbf, ksum,
                                                  lepe_w, lepe_b, actres, xamul);

    // out-proj + shortcut residual, in-place on d_out
    gemm_bt<5><<<dim3(128, 4), 256, 0, stream>>>(xamul, wt_out, out_b, outf, outf, nullptr, 512, 512);

    // cpe2 + LN2: x2 (=d_out) -> x3 (fp32 ws) + hln (bf16)
    cpe_ln_k<<<M_, 256, 0, stream>>>(outf, cpe2_w, cpe2_b, n2_g, n2_b, x3, hln);

    // MLP: fc1 (gelu) -> fc2 (+x3) -> d_out
    gemm_bt<4><<<dim3(128, 16), 256, 0, stream>>>(hln, wt_fc1, fc1_b, nullptr, h1, nullptr, 512, 2048);
    gemm_bt<5><<<dim3(128, 4),  256, 0, stream>>>(h1,  wt_fc2, fc2_b, x3, outf, nullptr, 2048, 512);

    (void)in_sizes; (void)n_in; (void)out_size; (void)ws_size;
}